// Round 5
// baseline (1915.885 us; speedup 1.0000x reference)
//
#include <hip/hip_runtime.h>
#include <cstdint>
#include <cstddef>

typedef unsigned long long u64;
typedef uint32_t u32;
typedef uint16_t u16;

// ---------------------------------------------------------------------------
// Binary AlexNet-1D. bq(w)=0.1*sign(w), bact(x)=sign(x). All binary layers are
// exact integer XNOR-popcount + f64 affine epilogue. Activations bitpacked as
// [N][L][C/64] u64. Conv sum = CIN*K - 2*popc(a^w); maxpool (stride==kernel,
// scale 0.1>0) commutes with the affine map, so pool the integer sums.
// Layer 1 (real f32 input): register-tiled f32 FMA pass (thread owns 16ch x
// 5 conv positions = one pool window) + uncertainty margin; near-zero outputs
// are recomputed in f64 by a fixup kernel, so sign decisions stay f64-exact.
// Layers 4..6 + fc1 + fc2 fused into one block-per-sample kernel (LDS).
// ---------------------------------------------------------------------------

#define CONV1_MARGIN 1e-4f

// -------------------- merged weight packing --------------------
// packs w[Cout][CIN][K] float -> wpk[K][Cout][CIN/64]; fc layers use K=1.
struct PackJob { const float* src; u64* dst; int Cout, CIN, K, waveBase; };
struct PackJobs { PackJob j[6]; int totalWaves; };

__global__ void pack_all_kernel(PackJobs P)
{
    int gtid = blockIdx.x * blockDim.x + threadIdx.x;
    int wid = gtid >> 6, lane = gtid & 63;
    if (wid >= P.totalWaves) return;
    int jj = 0;
    #pragma unroll
    for (int i = 1; i < 6; ++i) if (wid >= P.j[i].waveBase) jj = i;
    PackJob job = P.j[jj];
    int lw = wid - job.waveBase;
    int W = job.CIN >> 6;
    int wg = lw % W;
    int co = (lw / W) % job.Cout;
    int k  = lw / (W * job.Cout);
    int ci = wg * 64 + lane;
    bool sg = job.src[((size_t)co * job.CIN + ci) * job.K + k] >= 0.0f;
    u64 word = __ballot(sg);
    if (lane == 0) job.dst[lw] = word;
}

// fc1 weights: fw1[512][32] -> u32[512] sign bitmask (bit i = input i)
__global__ void packfc1_kernel(const float* __restrict__ fw1, u32* __restrict__ fw1pk)
{
    int o = blockIdx.x * blockDim.x + threadIdx.x;
    if (o >= 512) return;
    u32 wd = 0;
    #pragma unroll
    for (int i = 0; i < 32; ++i) wd |= (u32)(fw1[o * 32 + i] >= 0.0f) << i;
    fw1pk[o] = wd;
}

// -------------------- layer 1 --------------------
// grid (n=128, bl=2, chunk=16), block 256. Thread tid -> pooled output
// lp = 256*bl + tid for 16 channels [16*chunk, 16*chunk+16).
// conv positions l = 5*lp-2+j, j=0..4 (one pool window, thread-local max).
// x tile and +-1.0f weight tile staged in LDS; acc[16][5] in VGPRs.
__global__ __launch_bounds__(256, 4) void conv1_pass1_kernel(
    const float* __restrict__ x, const float* __restrict__ w1,
    const float* __restrict__ b, const float* __restrict__ sw,
    const float* __restrict__ sb,
    u16* __restrict__ opk16, u16* __restrict__ uflag16)
{
    __shared__ float xt[3 * 1440];
    __shared__ float wt[69 * 16];
    const int Lin = 2560, Lconv = 2406;
    int n = blockIdx.x, bl = blockIdx.y, chunk = blockIdx.z;
    int tid = threadIdx.x;
    int base = 1280 * bl - 2;

    // stage x tile (source index clamped; clamped values are only ever read
    // by conv positions that the pooling max later excludes)
    const float* xb = x + (size_t)n * 3 * Lin;
    for (int idx = tid; idx < 3 * 1440; idx += 256) {
        int ci = idx / 1440, rel = idx - ci * 1440;
        int src = min(max(base + rel, 0), Lin - 1);
        xt[idx] = xb[ci * Lin + src];
    }
    // stage weight signs as +-1.0f: wt[i][c], i = ci*23+kk
    for (int idx = tid; idx < 69 * 16; idx += 256) {
        int i = idx >> 4, c = idx & 15;
        wt[idx] = (w1[(size_t)(chunk * 16 + c) * 69 + i] >= 0.0f) ? 1.0f : -1.0f;
    }
    __syncthreads();

    float acc[16][5];
    #pragma unroll
    for (int c = 0; c < 16; ++c)
        #pragma unroll
        for (int j = 0; j < 5; ++j) acc[c][j] = 0.0f;

    const float* xrow = xt + 5 * tid;
    #pragma unroll 1
    for (int ci = 0; ci < 3; ++ci) {
        #pragma unroll 2
        for (int kk = 0; kk < 23; ++kk) {
            float xv[5];
            #pragma unroll
            for (int j = 0; j < 5; ++j)
                xv[j] = xrow[ci * 1440 + 7 * kk + j];
            const float4* wrow = (const float4*)(wt + (ci * 23 + kk) * 16);
            #pragma unroll
            for (int g = 0; g < 4; ++g) {
                float4 wv = wrow[g];
                #pragma unroll
                for (int j = 0; j < 5; ++j) {
                    acc[g * 4 + 0][j] = fmaf(xv[j], wv.x, acc[g * 4 + 0][j]);
                    acc[g * 4 + 1][j] = fmaf(xv[j], wv.y, acc[g * 4 + 1][j]);
                    acc[g * 4 + 2][j] = fmaf(xv[j], wv.z, acc[g * 4 + 2][j]);
                    acc[g * 4 + 3][j] = fmaf(xv[j], wv.w, acc[g * 4 + 3][j]);
                }
            }
        }
    }

    int lp = 256 * bl + tid;
    if (lp < 482) {
        u32 bits = 0, uncs = 0;
        #pragma unroll
        for (int c = 0; c < 16; ++c) {
            int co = chunk * 16 + c;
            float best = -1e30f;
            #pragma unroll
            for (int j = 0; j < 5; ++j) {
                int l = 5 * lp - 2 + j;
                if (l >= 0 && l < Lconv) best = fmaxf(best, acc[c][j]);
            }
            float v = ((sw[co] >= 0.0f) ? 0.1f : -0.1f) * (0.1f * best + b[co]) + sb[co];
            bits |= (v >= 0.0f ? 1u : 0u) << c;
            uncs |= (fabsf(v) < CONV1_MARGIN ? 1u : 0u) << c;
        }
        size_t widx = ((size_t)n * 482 + lp) * 16 + chunk;
        opk16[widx] = (u16)bits;
        uflag16[widx] = (u16)uncs;
    }
}

// Fixup: thread per packed u16 word; recompute flagged channels in f64.
__global__ void conv1_fixup_kernel(const float* __restrict__ x,
                                   const float* __restrict__ w1,
                                   const float* __restrict__ b,
                                   const float* __restrict__ sw,
                                   const float* __restrict__ sb,
                                   const u16* __restrict__ uflag16,
                                   u16* __restrict__ opk16)
{
    int idx = blockIdx.x * blockDim.x + threadIdx.x;
    if (idx >= 128 * 482 * 16) return;
    u32 f = uflag16[idx];
    if (f == 0) return;
    int chunk = idx & 15;
    int lp = (idx >> 4) % 482;
    int n = idx / (16 * 482);
    u32 word = opk16[idx];
    const float* xb = x + (size_t)n * 3 * 2560;
    while (f) {
        int c = __ffs(f) - 1;
        f &= f - 1;
        int co = chunk * 16 + c;
        const float* wp = w1 + (size_t)co * 69;
        double best = -1e300;
        for (int t = 0; t < 5; ++t) {
            int gl = 5 * lp - 2 + t;
            if (gl < 0 || gl >= 2406) continue;
            double s = 0.0;
            #pragma unroll
            for (int ci = 0; ci < 3; ++ci) {
                const float* xp = xb + ci * 2560 + gl;
                const float* wq = wp + ci * 23;
                #pragma unroll
                for (int kk = 0; kk < 23; ++kk) {
                    double xv = (double)xp[kk * 7];
                    s += (wq[kk] >= 0.0f) ? xv : -xv;
                }
            }
            best = fmax(best, s);
        }
        double v = ((sw[co] >= 0.0f) ? 0.1 : -0.1) * (0.1 * best + (double)b[co]) + (double)sb[co];
        u32 bit = (v >= 0.0) ? 1u : 0u;
        word = (word & ~(1u << c)) | (bit << c);
    }
    opk16[idx] = word;
}

// -------------------- binary conv layers 2,3 (XNOR-popcount) ---------------
// One wave = 64 output channels x LPW pooled positions at one (n,og).
template<int K, int DIL, int PK, int PP, int W, int LPW>
__global__ void bconv_bit_kernel(const u64* __restrict__ apk,  // [N][Lin][W]
                                 const u64* __restrict__ wpk,  // [K][Cout][W]
                                 const float* __restrict__ b,
                                 const float* __restrict__ sw,
                                 const float* __restrict__ sb,
                                 u64* __restrict__ opk,        // [N][Lout][Cout/64]
                                 int Cout, int Lin, int Lconv, int Lout,
                                 int NLPG, int nwaves)
{
    int wid = __builtin_amdgcn_readfirstlane(
        (int)(blockIdx.x * (blockDim.x >> 6)) + (int)(threadIdx.x >> 6));
    int lane = threadIdx.x & 63;
    if (wid >= nwaves) return;
    int WOUT = Cout >> 6;
    int og = wid % WOUT;
    int lpg = (wid / WOUT) % NLPG;
    int n  = wid / (WOUT * NLPG);
    int lp0 = lpg * LPW;
    int co = og * 64 + lane;

    const u64* ab = apk + (size_t)n * Lin * W;
    int cnt[LPW][PK];
    #pragma unroll
    for (int j = 0; j < LPW; ++j)
        #pragma unroll
        for (int t = 0; t < PK; ++t) cnt[j][t] = 0;

    #pragma unroll
    for (int k = 0; k < K; ++k) {
        u64 ww[W];
        #pragma unroll
        for (int w = 0; w < W; ++w)
            ww[w] = wpk[((size_t)k * Cout + co) * W + w];
        #pragma unroll
        for (int j = 0; j < LPW; ++j) {
            int lp = lp0 + j;
            #pragma unroll
            for (int t = 0; t < PK; ++t) {
                int l = lp * PK - PP + t;
                if (lp >= Lout || l < 0 || l >= Lconv) continue;
                const u64* ap = ab + (size_t)(l + k * DIL) * W;
                #pragma unroll
                for (int w = 0; w < W; ++w)
                    cnt[j][t] += __popcll(ap[w] ^ ww[w]);
            }
        }
    }
    const int CINK = W * 64 * K;
    #pragma unroll
    for (int j = 0; j < LPW; ++j) {
        int lp = lp0 + j;
        int best = -2147483647;
        #pragma unroll
        for (int t = 0; t < PK; ++t) {
            int l = lp * PK - PP + t;
            if (l < 0 || l >= Lconv) continue;
            int ksum = CINK - 2 * cnt[j][t];
            best = (ksum > best) ? ksum : best;
        }
        bool bit = false;
        if (lp < Lout) {
            double conv = 0.1 * (double)best + (double)b[co];
            double v = ((sw[co] >= 0.0f) ? 0.1 : -0.1) * conv + (double)sb[co];
            bit = (v >= 0.0);
        }
        u64 word = __ballot(bit);
        if (lp < Lout && lane == 0)
            opk[((size_t)n * Lout + lp) * WOUT + og] = word;
    }
}

// -------------------- fused tail: layers 4,5,6 + fc1 + fc2 -----------------
// One block (256 threads) per sample n; intermediates live in LDS.
__global__ __launch_bounds__(256) void tail_kernel(
    const u64* __restrict__ a3,      // [128][46][4]
    const u64* __restrict__ wpk4,    // [5][256][4]
    const u64* __restrict__ wpk5,    // [5][256][4]
    const u64* __restrict__ wpk6,    // [3][8][4]
    const float* __restrict__ b4, const float* __restrict__ sw4, const float* __restrict__ sb4,
    const float* __restrict__ b5, const float* __restrict__ sw5, const float* __restrict__ sb5,
    const float* __restrict__ b6, const float* __restrict__ sw6, const float* __restrict__ sb6,
    const u32* __restrict__ fw1pk,   // [512]
    const float* __restrict__ fsw1, const float* __restrict__ fsb1,
    const u64* __restrict__ fpk2,    // [1000][8]
    const float* __restrict__ fsw2, const float* __restrict__ fsb2,
    float* __restrict__ out)         // [128][1000]
{
    __shared__ u64 sA[46 * 4];   // layer-4 input
    __shared__ u64 sB[42 * 4];   // layer-4 output
    __shared__ u64 sC[13 * 4];   // layer-5 output
    __shared__ u32 sA6;          // layer-6 output, 32 bits (bit = co*4+lp)
    __shared__ u64 sH[8];        // fc1 output, 512 bits
    int n = blockIdx.x, tid = threadIdx.x, lane = tid & 63, wv = tid >> 6;

    for (int i = tid; i < 46 * 4; i += 256) sA[i] = a3[(size_t)n * 46 * 4 + i];
    __syncthreads();

    // ---- layer 4: K=5, dil=1, no pool, Lconv=Lout=42, thread = channel ----
    {
        u64 ww[5][4];
        #pragma unroll
        for (int k = 0; k < 5; ++k)
            #pragma unroll
            for (int w = 0; w < 4; ++w)
                ww[k][w] = wpk4[((size_t)k * 256 + tid) * 4 + w];
        double bc = b4[tid];
        double swc = (sw4[tid] >= 0.0f) ? 0.1 : -0.1;
        double sbc = sb4[tid];
        for (int lp = 0; lp < 42; ++lp) {
            int cnt = 0;
            #pragma unroll
            for (int k = 0; k < 5; ++k)
                #pragma unroll
                for (int w = 0; w < 4; ++w)
                    cnt += __popcll(sA[(lp + k) * 4 + w] ^ ww[k][w]);
            int ksum = 256 * 5 - 2 * cnt;
            double v = swc * (0.1 * ksum + bc) + sbc;
            u64 word = __ballot(v >= 0.0);
            if (lane == 0) sB[lp * 4 + wv] = word;
        }
    }
    __syncthreads();

    // ---- layer 5: K=5, pool(3,1), Lconv=38, Lout=13, thread = channel ----
    {
        u64 ww[5][4];
        #pragma unroll
        for (int k = 0; k < 5; ++k)
            #pragma unroll
            for (int w = 0; w < 4; ++w)
                ww[k][w] = wpk5[((size_t)k * 256 + tid) * 4 + w];
        double bc = b5[tid];
        double swc = (sw5[tid] >= 0.0f) ? 0.1 : -0.1;
        double sbc = sb5[tid];
        for (int lp = 0; lp < 13; ++lp) {
            int best = -2147483647;
            #pragma unroll
            for (int t = 0; t < 3; ++t) {
                int l = 3 * lp - 1 + t;
                if (l < 0 || l >= 38) continue;
                int cnt = 0;
                #pragma unroll
                for (int k = 0; k < 5; ++k)
                    #pragma unroll
                    for (int w = 0; w < 4; ++w)
                        cnt += __popcll(sB[(l + k) * 4 + w] ^ ww[k][w]);
                int ksum = 256 * 5 - 2 * cnt;
                best = (ksum > best) ? ksum : best;
            }
            double v = swc * (0.1 * best + bc) + sbc;
            u64 word = __ballot(v >= 0.0);
            if (lane == 0) sC[lp * 4 + wv] = word;
        }
    }
    __syncthreads();

    // ---- layer 6: Cout=8, K=3, pool(3,1), Lconv=11, Lout=4 ----
    if (tid < 32) {
        int co = tid >> 2, lp = tid & 3;
        int best = -2147483647;
        for (int t = 0; t < 3; ++t) {
            int l = 3 * lp - 1 + t;
            if (l < 0 || l >= 11) continue;
            int cnt = 0;
            #pragma unroll
            for (int k = 0; k < 3; ++k)
                #pragma unroll
                for (int w = 0; w < 4; ++w)
                    cnt += __popcll(sC[(l + k) * 4 + w] ^ wpk6[((size_t)k * 8 + co) * 4 + w]);
            int ksum = 256 * 3 - 2 * cnt;
            best = (ksum > best) ? ksum : best;
        }
        double v = ((sw6[co] >= 0.0f) ? 0.1 : -0.1) * (0.1 * best + (double)b6[co]) + (double)sb6[co];
        u64 word = __ballot(v >= 0.0);   // bit index = tid = co*4+lp (reshape order)
        if (tid == 0) sA6 = (u32)word;
    }
    __syncthreads();

    // ---- fc1: 512 outputs, 32-bit xnor-popcount ----
    {
        u32 a6w = sA6;
        #pragma unroll
        for (int p = 0; p < 2; ++p) {
            int o = tid + p * 256;
            int k = 32 - 2 * __popc(a6w ^ fw1pk[o]);
            double v = ((fsw1[o] >= 0.0f) ? 0.1 : -0.1) * (0.1 * (double)k) + (double)fsb1[o];
            u64 word = __ballot(v >= 0.0);
            if (lane == 0) sH[p * 4 + wv] = word;
        }
    }
    __syncthreads();

    // ---- fc2: 1000 outputs, 512-bit xnor-popcount, f32 store ----
    {
        u64 h[8];
        #pragma unroll
        for (int w = 0; w < 8; ++w) h[w] = sH[w];
        #pragma unroll
        for (int p = 0; p < 4; ++p) {
            int o = tid + p * 256;
            if (o < 1000) {
                int cnt = 0;
                #pragma unroll
                for (int w = 0; w < 8; ++w)
                    cnt += __popcll(h[w] ^ fpk2[(size_t)o * 8 + w]);
                int k = 512 - 2 * cnt;
                double v = ((fsw2[o] >= 0.0f) ? 0.1 : -0.1) * (0.1 * (double)k) + (double)fsb2[o];
                out[(size_t)n * 1000 + o] = (float)v;
            }
        }
    }
}

extern "C" void kernel_launch(void* const* d_in, const int* in_sizes, int n_in,
                              void* d_out, int out_size, void* d_ws, size_t ws_size,
                              hipStream_t stream) {
    const float* x = (const float*)d_in[0];
    const float *w[6], *b[6], *sw[6], *sb[6];
    for (int i = 0; i < 6; ++i) {
        w[i]  = (const float*)d_in[1 + 4 * i];
        b[i]  = (const float*)d_in[2 + 4 * i];
        sw[i] = (const float*)d_in[3 + 4 * i];
        sb[i] = (const float*)d_in[4 + 4 * i];
    }
    const float* fw1  = (const float*)d_in[25];
    const float* fsw1 = (const float*)d_in[26];
    const float* fsb1 = (const float*)d_in[27];
    const float* fw2  = (const float*)d_in[28];
    const float* fsw2 = (const float*)d_in[29];
    const float* fsb2 = (const float*)d_in[30];
    float* out = (float*)d_out;
    (void)in_sizes; (void)n_in; (void)out_size; (void)ws_size;

    char* wsbase = (char*)d_ws;
    size_t off = 0;
    auto alloc = [&](size_t bytes) -> char* {
        char* p = wsbase + off;
        off = (off + bytes + 255) & ~(size_t)255;
        return p;
    };
    u64* wpk2 = (u64*)alloc((size_t)13 * 256 * 4 * 8);
    u64* wpk3 = (u64*)alloc((size_t)7 * 256 * 4 * 8);
    u64* wpk4 = (u64*)alloc((size_t)5 * 256 * 4 * 8);
    u64* wpk5 = (u64*)alloc((size_t)5 * 256 * 4 * 8);
    u64* wpk6 = (u64*)alloc((size_t)3 * 8 * 4 * 8);
    u64* fpk2 = (u64*)alloc((size_t)1000 * 8 * 8);
    u32* fw1pk = (u32*)alloc((size_t)512 * 4);
    u16* uflag16 = (u16*)alloc((size_t)128 * 482 * 16 * 2);
    u64* a1   = (u64*)alloc((size_t)128 * 482 * 4 * 8);
    u64* a2   = (u64*)alloc((size_t)128 * 149 * 4 * 8);
    u64* a3   = (u64*)alloc((size_t)128 * 46 * 4 * 8);
    u16* opk16 = (u16*)a1;  // u16 word (co/16) aliases u64 word (co/64) bits

    const int BLK = 256;
    auto blocksForWaves = [](int nwaves) { return dim3((unsigned)((nwaves * 64 + 255) / 256)); };
    auto blocksForThreads = [](int n) { return dim3((unsigned)((n + 255) / 256)); };

    // merged weight packing (fc2 job expressed as K=1)
    {
        PackJobs P;
        int base = 0;
        auto setJob = [&](int i, const float* src, u64* dst, int Cout, int CIN, int K) {
            P.j[i] = {src, dst, Cout, CIN, K, base};
            base += K * Cout * (CIN >> 6);
        };
        setJob(0, w[1], wpk2, 256, 256, 13);
        setJob(1, w[2], wpk3, 256, 256, 7);
        setJob(2, w[3], wpk4, 256, 256, 5);
        setJob(3, w[4], wpk5, 256, 256, 5);
        setJob(4, w[5], wpk6, 8, 256, 3);
        setJob(5, fw2, fpk2, 1000, 512, 1);
        P.totalWaves = base;
        pack_all_kernel<<<blocksForWaves(base), BLK, 0, stream>>>(P);
    }
    packfc1_kernel<<<dim3(2), BLK, 0, stream>>>(fw1, fw1pk);

    // layer 1: register-tiled f32 pass + f64 fixup of near-zero outputs
    conv1_pass1_kernel<<<dim3(128, 2, 16), BLK, 0, stream>>>(
        x, w[0], b[0], sw[0], sb[0], opk16, uflag16);
    conv1_fixup_kernel<<<blocksForThreads(128 * 482 * 16), BLK, 0, stream>>>(
        x, w[0], b[0], sw[0], sb[0], uflag16, opk16);

    // layer 2: K=13 dil=3 pool(3,1): Lin=482 Lconv=446 Lout=149
    {
        const int NLPG = (149 + 3) / 4;
        int nw = 128 * NLPG * 4;
        bconv_bit_kernel<13, 3, 3, 1, 4, 4><<<blocksForWaves(nw), BLK, 0, stream>>>(
            a1, wpk2, b[1], sw[1], sb[1], a2, 256, 482, 446, 149, NLPG, nw);
    }
    // layer 3: K=7 dil=2 pool(3,1): Lin=149 Lconv=137 Lout=46
    {
        const int NLPG = (46 + 3) / 4;
        int nw = 128 * NLPG * 4;
        bconv_bit_kernel<7, 2, 3, 1, 4, 4><<<blocksForWaves(nw), BLK, 0, stream>>>(
            a2, wpk3, b[2], sw[2], sb[2], a3, 256, 149, 137, 46, NLPG, nw);
    }
    // fused tail: layers 4,5,6 + fc1 + fc2
    tail_kernel<<<dim3(128), BLK, 0, stream>>>(
        a3, wpk4, wpk5, wpk6,
        b[3], sw[3], sb[3], b[4], sw[4], sb[4], b[5], sw[5], sb[5],
        fw1pk, fsw1, fsb1, fpk2, fsw2, fsb2, out);
}

// Round 6
// 389.379 us; speedup vs baseline: 4.9204x; 4.9204x over previous
//
#include <hip/hip_runtime.h>
#include <cstdint>
#include <cstddef>

typedef unsigned long long u64;
typedef uint32_t u32;
typedef uint16_t u16;

// ---------------------------------------------------------------------------
// Binary AlexNet-1D. bq(w)=0.1*sign(w), bact(x)=sign(x). All binary layers are
// exact integer XNOR-popcount + f64 affine epilogue. Activations bitpacked as
// [N][L][C/64] u64. Conv sum = CIN*K - 2*popc(a^w); maxpool (stride==kernel,
// scale 0.1>0) commutes with the affine map, so pool the integer sums.
// Layer 1 (real f32 input): register-tiled f32 FMA pass (thread owns 16ch x
// 5 conv positions = one pool window; acc[16][5] in VGPRs, weights +-1.0f via
// wave-uniform scalar loads, x via LDS tile) + uncertainty margin; near-zero
// outputs are recomputed in f64 by a fixup kernel (sign stays f64-exact).
// Layers 4..6 + fc1 + fc2 fused into one block-per-sample kernel (LDS).
// ---------------------------------------------------------------------------

#define CONV1_MARGIN 1e-4f

// -------------------- merged weight packing --------------------
// packs w[Cout][CIN][K] float -> wpk[K][Cout][CIN/64]; fc layers use K=1.
struct PackJob { const float* src; u64* dst; int Cout, CIN, K, waveBase; };
struct PackJobs { PackJob j[6]; int totalWaves; };

__global__ void pack_all_kernel(PackJobs P)
{
    int gtid = blockIdx.x * blockDim.x + threadIdx.x;
    int wid = gtid >> 6, lane = gtid & 63;
    if (wid >= P.totalWaves) return;
    int jj = 0;
    #pragma unroll
    for (int i = 1; i < 6; ++i) if (wid >= P.j[i].waveBase) jj = i;
    PackJob job = P.j[jj];
    int lw = wid - job.waveBase;
    int W = job.CIN >> 6;
    int wg = lw % W;
    int co = (lw / W) % job.Cout;
    int k  = lw / (W * job.Cout);
    int ci = wg * 64 + lane;
    bool sg = job.src[((size_t)co * job.CIN + ci) * job.K + k] >= 0.0f;
    u64 word = __ballot(sg);
    if (lane == 0) job.dst[lw] = word;
}

// fc1 weights: fw1[512][32] -> u32[512] sign bitmask (bit i = input i)
__global__ void packfc1_kernel(const float* __restrict__ fw1, u32* __restrict__ fw1pk)
{
    int o = blockIdx.x * blockDim.x + threadIdx.x;
    if (o >= 512) return;
    u32 wd = 0;
    #pragma unroll
    for (int i = 0; i < 32; ++i) wd |= (u32)(fw1[o * 32 + i] >= 0.0f) << i;
    fw1pk[o] = wd;
}

// layer-1 weight signs as f32 +-1.0: sgnf[chunk][i][c], chunk=co/16, c=co%16
__global__ void pack_sgn1_kernel(const float* __restrict__ w1, float* __restrict__ sgnf)
{
    int idx = blockIdx.x * blockDim.x + threadIdx.x;
    if (idx >= 256 * 69) return;
    int i = idx % 69, co = idx / 69;
    sgnf[(size_t)(co >> 4) * 69 * 16 + i * 16 + (co & 15)] =
        (w1[(size_t)co * 69 + i] >= 0.0f) ? 1.0f : -1.0f;
}

// -------------------- layer 1 --------------------
// grid (n=128, bl=2, chunk=16), block 256. Thread tid -> pooled output
// lp = 256*bl + tid for 16 channels [16*chunk, 16*chunk+16).
// conv positions l = 5*lp-2+j, j=0..4 (one pool window, thread-local max).
// x tile in LDS; weights wave-uniform scalar loads; acc[16][5] in VGPRs.
__global__ __launch_bounds__(256) void conv1_pass1_kernel(
    const float* __restrict__ x, const float* __restrict__ sgnf,
    const float* __restrict__ b, const float* __restrict__ sw,
    const float* __restrict__ sb,
    u16* __restrict__ opk16, u16* __restrict__ uflag16)
{
    __shared__ float xt[3 * 1440];
    const int Lin = 2560, Lconv = 2406;
    int n = blockIdx.x, bl = blockIdx.y, chunk = blockIdx.z;
    int tid = threadIdx.x;
    int base = 1280 * bl - 2;

    // stage x tile (source index clamped; clamped values are only ever read
    // by conv positions that the pooling max later excludes)
    const float* xb = x + (size_t)n * 3 * Lin;
    for (int idx = tid; idx < 3 * 1440; idx += 256) {
        int ci = idx / 1440, rel = idx - ci * 1440;
        int src = min(max(base + rel, 0), Lin - 1);
        xt[idx] = xb[ci * Lin + src];
    }
    __syncthreads();

    float acc[16][5];
    #pragma unroll
    for (int c = 0; c < 16; ++c)
        #pragma unroll
        for (int j = 0; j < 5; ++j) acc[c][j] = 0.0f;

    const float* xrow = xt + 5 * tid;
    const float* sgp = sgnf + (size_t)chunk * 69 * 16;   // wave-uniform
    #pragma unroll 1
    for (int ci = 0; ci < 3; ++ci) {
        #pragma unroll
        for (int kk = 0; kk < 23; ++kk) {
            float xv[5];
            #pragma unroll
            for (int j = 0; j < 5; ++j)
                xv[j] = xrow[ci * 1440 + 7 * kk + j];
            #pragma unroll
            for (int c = 0; c < 16; ++c) {
                float wv = sgp[(ci * 23 + kk) * 16 + c];   // s_load (uniform)
                #pragma unroll
                for (int j = 0; j < 5; ++j)
                    acc[c][j] = fmaf(xv[j], wv, acc[c][j]);
            }
        }
    }

    int lp = 256 * bl + tid;
    if (lp < 482) {
        u32 bits = 0, uncs = 0;
        #pragma unroll
        for (int c = 0; c < 16; ++c) {
            int co = chunk * 16 + c;
            float best = -1e30f;
            #pragma unroll
            for (int j = 0; j < 5; ++j) {
                int l = 5 * lp - 2 + j;
                if (l >= 0 && l < Lconv) best = fmaxf(best, acc[c][j]);
            }
            float v = ((sw[co] >= 0.0f) ? 0.1f : -0.1f) * (0.1f * best + b[co]) + sb[co];
            bits |= (v >= 0.0f ? 1u : 0u) << c;
            uncs |= (fabsf(v) < CONV1_MARGIN ? 1u : 0u) << c;
        }
        size_t widx = ((size_t)n * 482 + lp) * 16 + chunk;
        opk16[widx] = (u16)bits;
        uflag16[widx] = (u16)uncs;
    }
}

// Fixup: thread per packed u16 word; recompute flagged channels in f64.
__global__ void conv1_fixup_kernel(const float* __restrict__ x,
                                   const float* __restrict__ w1,
                                   const float* __restrict__ b,
                                   const float* __restrict__ sw,
                                   const float* __restrict__ sb,
                                   const u16* __restrict__ uflag16,
                                   u16* __restrict__ opk16)
{
    int idx = blockIdx.x * blockDim.x + threadIdx.x;
    if (idx >= 128 * 482 * 16) return;
    u32 f = uflag16[idx];
    if (f == 0) return;
    int chunk = idx & 15;
    int lp = (idx >> 4) % 482;
    int n = idx / (16 * 482);
    u32 word = opk16[idx];
    const float* xb = x + (size_t)n * 3 * 2560;
    while (f) {
        int c = __ffs(f) - 1;
        f &= f - 1;
        int co = chunk * 16 + c;
        const float* wp = w1 + (size_t)co * 69;
        double best = -1e300;
        for (int t = 0; t < 5; ++t) {
            int gl = 5 * lp - 2 + t;
            if (gl < 0 || gl >= 2406) continue;
            double s = 0.0;
            #pragma unroll
            for (int ci = 0; ci < 3; ++ci) {
                const float* xp = xb + ci * 2560 + gl;
                const float* wq = wp + ci * 23;
                #pragma unroll
                for (int kk = 0; kk < 23; ++kk) {
                    double xv = (double)xp[kk * 7];
                    s += (wq[kk] >= 0.0f) ? xv : -xv;
                }
            }
            best = fmax(best, s);
        }
        double v = ((sw[co] >= 0.0f) ? 0.1 : -0.1) * (0.1 * best + (double)b[co]) + (double)sb[co];
        u32 bit = (v >= 0.0) ? 1u : 0u;
        word = (word & ~(1u << c)) | (bit << c);
    }
    opk16[idx] = word;
}

// -------------------- binary conv layers 2,3 (XNOR-popcount) ---------------
// One wave = 64 output channels x LPW pooled positions at one (n,og).
template<int K, int DIL, int PK, int PP, int W, int LPW>
__global__ void bconv_bit_kernel(const u64* __restrict__ apk,  // [N][Lin][W]
                                 const u64* __restrict__ wpk,  // [K][Cout][W]
                                 const float* __restrict__ b,
                                 const float* __restrict__ sw,
                                 const float* __restrict__ sb,
                                 u64* __restrict__ opk,        // [N][Lout][Cout/64]
                                 int Cout, int Lin, int Lconv, int Lout,
                                 int NLPG, int nwaves)
{
    int wid = __builtin_amdgcn_readfirstlane(
        (int)(blockIdx.x * (blockDim.x >> 6)) + (int)(threadIdx.x >> 6));
    int lane = threadIdx.x & 63;
    if (wid >= nwaves) return;
    int WOUT = Cout >> 6;
    int og = wid % WOUT;
    int lpg = (wid / WOUT) % NLPG;
    int n  = wid / (WOUT * NLPG);
    int lp0 = lpg * LPW;
    int co = og * 64 + lane;

    const u64* ab = apk + (size_t)n * Lin * W;
    int cnt[LPW][PK];
    #pragma unroll
    for (int j = 0; j < LPW; ++j)
        #pragma unroll
        for (int t = 0; t < PK; ++t) cnt[j][t] = 0;

    #pragma unroll
    for (int k = 0; k < K; ++k) {
        u64 ww[W];
        #pragma unroll
        for (int w = 0; w < W; ++w)
            ww[w] = wpk[((size_t)k * Cout + co) * W + w];
        #pragma unroll
        for (int j = 0; j < LPW; ++j) {
            int lp = lp0 + j;
            #pragma unroll
            for (int t = 0; t < PK; ++t) {
                int l = lp * PK - PP + t;
                if (lp >= Lout || l < 0 || l >= Lconv) continue;
                const u64* ap = ab + (size_t)(l + k * DIL) * W;
                #pragma unroll
                for (int w = 0; w < W; ++w)
                    cnt[j][t] += __popcll(ap[w] ^ ww[w]);
            }
        }
    }
    const int CINK = W * 64 * K;
    #pragma unroll
    for (int j = 0; j < LPW; ++j) {
        int lp = lp0 + j;
        int best = -2147483647;
        #pragma unroll
        for (int t = 0; t < PK; ++t) {
            int l = lp * PK - PP + t;
            if (l < 0 || l >= Lconv) continue;
            int ksum = CINK - 2 * cnt[j][t];
            best = (ksum > best) ? ksum : best;
        }
        bool bit = false;
        if (lp < Lout) {
            double conv = 0.1 * (double)best + (double)b[co];
            double v = ((sw[co] >= 0.0f) ? 0.1 : -0.1) * conv + (double)sb[co];
            bit = (v >= 0.0);
        }
        u64 word = __ballot(bit);
        if (lp < Lout && lane == 0)
            opk[((size_t)n * Lout + lp) * WOUT + og] = word;
    }
}

// -------------------- fused tail: layers 4,5,6 + fc1 + fc2 -----------------
// One block (256 threads) per sample n; intermediates live in LDS.
__global__ __launch_bounds__(256) void tail_kernel(
    const u64* __restrict__ a3,      // [128][46][4]
    const u64* __restrict__ wpk4,    // [5][256][4]
    const u64* __restrict__ wpk5,    // [5][256][4]
    const u64* __restrict__ wpk6,    // [3][8][4]
    const float* __restrict__ b4, const float* __restrict__ sw4, const float* __restrict__ sb4,
    const float* __restrict__ b5, const float* __restrict__ sw5, const float* __restrict__ sb5,
    const float* __restrict__ b6, const float* __restrict__ sw6, const float* __restrict__ sb6,
    const u32* __restrict__ fw1pk,   // [512]
    const float* __restrict__ fsw1, const float* __restrict__ fsb1,
    const u64* __restrict__ fpk2,    // [1000][8]
    const float* __restrict__ fsw2, const float* __restrict__ fsb2,
    float* __restrict__ out)         // [128][1000]
{
    __shared__ u64 sA[46 * 4];   // layer-4 input
    __shared__ u64 sB[42 * 4];   // layer-4 output
    __shared__ u64 sC[13 * 4];   // layer-5 output
    __shared__ u32 sA6;          // layer-6 output, 32 bits (bit = co*4+lp)
    __shared__ u64 sH[8];        // fc1 output, 512 bits
    int n = blockIdx.x, tid = threadIdx.x, lane = tid & 63, wv = tid >> 6;

    for (int i = tid; i < 46 * 4; i += 256) sA[i] = a3[(size_t)n * 46 * 4 + i];
    __syncthreads();

    // ---- layer 4: K=5, dil=1, no pool, Lconv=Lout=42, thread = channel ----
    {
        u64 ww[5][4];
        #pragma unroll
        for (int k = 0; k < 5; ++k)
            #pragma unroll
            for (int w = 0; w < 4; ++w)
                ww[k][w] = wpk4[((size_t)k * 256 + tid) * 4 + w];
        double bc = b4[tid];
        double swc = (sw4[tid] >= 0.0f) ? 0.1 : -0.1;
        double sbc = sb4[tid];
        for (int lp = 0; lp < 42; ++lp) {
            int cnt = 0;
            #pragma unroll
            for (int k = 0; k < 5; ++k)
                #pragma unroll
                for (int w = 0; w < 4; ++w)
                    cnt += __popcll(sA[(lp + k) * 4 + w] ^ ww[k][w]);
            int ksum = 256 * 5 - 2 * cnt;
            double v = swc * (0.1 * ksum + bc) + sbc;
            u64 word = __ballot(v >= 0.0);
            if (lane == 0) sB[lp * 4 + wv] = word;
        }
    }
    __syncthreads();

    // ---- layer 5: K=5, pool(3,1), Lconv=38, Lout=13, thread = channel ----
    {
        u64 ww[5][4];
        #pragma unroll
        for (int k = 0; k < 5; ++k)
            #pragma unroll
            for (int w = 0; w < 4; ++w)
                ww[k][w] = wpk5[((size_t)k * 256 + tid) * 4 + w];
        double bc = b5[tid];
        double swc = (sw5[tid] >= 0.0f) ? 0.1 : -0.1;
        double sbc = sb5[tid];
        for (int lp = 0; lp < 13; ++lp) {
            int best = -2147483647;
            #pragma unroll
            for (int t = 0; t < 3; ++t) {
                int l = 3 * lp - 1 + t;
                if (l < 0 || l >= 38) continue;
                int cnt = 0;
                #pragma unroll
                for (int k = 0; k < 5; ++k)
                    #pragma unroll
                    for (int w = 0; w < 4; ++w)
                        cnt += __popcll(sB[(l + k) * 4 + w] ^ ww[k][w]);
                int ksum = 256 * 5 - 2 * cnt;
                best = (ksum > best) ? ksum : best;
            }
            double v = swc * (0.1 * best + bc) + sbc;
            u64 word = __ballot(v >= 0.0);
            if (lane == 0) sC[lp * 4 + wv] = word;
        }
    }
    __syncthreads();

    // ---- layer 6: Cout=8, K=3, pool(3,1), Lconv=11, Lout=4 ----
    if (tid < 32) {
        int co = tid >> 2, lp = tid & 3;
        int best = -2147483647;
        for (int t = 0; t < 3; ++t) {
            int l = 3 * lp - 1 + t;
            if (l < 0 || l >= 11) continue;
            int cnt = 0;
            #pragma unroll
            for (int k = 0; k < 3; ++k)
                #pragma unroll
                for (int w = 0; w < 4; ++w)
                    cnt += __popcll(sC[(l + k) * 4 + w] ^ wpk6[((size_t)k * 8 + co) * 4 + w]);
            int ksum = 256 * 3 - 2 * cnt;
            best = (ksum > best) ? ksum : best;
        }
        double v = ((sw6[co] >= 0.0f) ? 0.1 : -0.1) * (0.1 * best + (double)b6[co]) + (double)sb6[co];
        u64 word = __ballot(v >= 0.0);   // bit index = tid = co*4+lp (reshape order)
        if (tid == 0) sA6 = (u32)word;
    }
    __syncthreads();

    // ---- fc1: 512 outputs, 32-bit xnor-popcount ----
    {
        u32 a6w = sA6;
        #pragma unroll
        for (int p = 0; p < 2; ++p) {
            int o = tid + p * 256;
            int k = 32 - 2 * __popc(a6w ^ fw1pk[o]);
            double v = ((fsw1[o] >= 0.0f) ? 0.1 : -0.1) * (0.1 * (double)k) + (double)fsb1[o];
            u64 word = __ballot(v >= 0.0);
            if (lane == 0) sH[p * 4 + wv] = word;
        }
    }
    __syncthreads();

    // ---- fc2: 1000 outputs, 512-bit xnor-popcount, f32 store ----
    {
        u64 h[8];
        #pragma unroll
        for (int w = 0; w < 8; ++w) h[w] = sH[w];
        #pragma unroll
        for (int p = 0; p < 4; ++p) {
            int o = tid + p * 256;
            if (o < 1000) {
                int cnt = 0;
                #pragma unroll
                for (int w = 0; w < 8; ++w)
                    cnt += __popcll(h[w] ^ fpk2[(size_t)o * 8 + w]);
                int k = 512 - 2 * cnt;
                double v = ((fsw2[o] >= 0.0f) ? 0.1 : -0.1) * (0.1 * (double)k) + (double)fsb2[o];
                out[(size_t)n * 1000 + o] = (float)v;
            }
        }
    }
}

extern "C" void kernel_launch(void* const* d_in, const int* in_sizes, int n_in,
                              void* d_out, int out_size, void* d_ws, size_t ws_size,
                              hipStream_t stream) {
    const float* x = (const float*)d_in[0];
    const float *w[6], *b[6], *sw[6], *sb[6];
    for (int i = 0; i < 6; ++i) {
        w[i]  = (const float*)d_in[1 + 4 * i];
        b[i]  = (const float*)d_in[2 + 4 * i];
        sw[i] = (const float*)d_in[3 + 4 * i];
        sb[i] = (const float*)d_in[4 + 4 * i];
    }
    const float* fw1  = (const float*)d_in[25];
    const float* fsw1 = (const float*)d_in[26];
    const float* fsb1 = (const float*)d_in[27];
    const float* fw2  = (const float*)d_in[28];
    const float* fsw2 = (const float*)d_in[29];
    const float* fsb2 = (const float*)d_in[30];
    float* out = (float*)d_out;
    (void)in_sizes; (void)n_in; (void)out_size; (void)ws_size;

    char* wsbase = (char*)d_ws;
    size_t off = 0;
    auto alloc = [&](size_t bytes) -> char* {
        char* p = wsbase + off;
        off = (off + bytes + 255) & ~(size_t)255;
        return p;
    };
    u64* wpk2 = (u64*)alloc((size_t)13 * 256 * 4 * 8);
    u64* wpk3 = (u64*)alloc((size_t)7 * 256 * 4 * 8);
    u64* wpk4 = (u64*)alloc((size_t)5 * 256 * 4 * 8);
    u64* wpk5 = (u64*)alloc((size_t)5 * 256 * 4 * 8);
    u64* wpk6 = (u64*)alloc((size_t)3 * 8 * 4 * 8);
    u64* fpk2 = (u64*)alloc((size_t)1000 * 8 * 8);
    u32* fw1pk = (u32*)alloc((size_t)512 * 4);
    float* sgnf = (float*)alloc((size_t)16 * 69 * 16 * 4);
    u16* uflag16 = (u16*)alloc((size_t)128 * 482 * 16 * 2);
    u64* a1   = (u64*)alloc((size_t)128 * 482 * 4 * 8);
    u64* a2   = (u64*)alloc((size_t)128 * 149 * 4 * 8);
    u64* a3   = (u64*)alloc((size_t)128 * 46 * 4 * 8);
    u16* opk16 = (u16*)a1;  // u16 word (co/16) aliases u64 word (co/64) bits

    const int BLK = 256;
    auto blocksForWaves = [](int nwaves) { return dim3((unsigned)((nwaves * 64 + 255) / 256)); };
    auto blocksForThreads = [](int n) { return dim3((unsigned)((n + 255) / 256)); };

    // merged weight packing (fc2 job expressed as K=1)
    {
        PackJobs P;
        int base = 0;
        auto setJob = [&](int i, const float* src, u64* dst, int Cout, int CIN, int K) {
            P.j[i] = {src, dst, Cout, CIN, K, base};
            base += K * Cout * (CIN >> 6);
        };
        setJob(0, w[1], wpk2, 256, 256, 13);
        setJob(1, w[2], wpk3, 256, 256, 7);
        setJob(2, w[3], wpk4, 256, 256, 5);
        setJob(3, w[4], wpk5, 256, 256, 5);
        setJob(4, w[5], wpk6, 8, 256, 3);
        setJob(5, fw2, fpk2, 1000, 512, 1);
        P.totalWaves = base;
        pack_all_kernel<<<blocksForWaves(base), BLK, 0, stream>>>(P);
    }
    packfc1_kernel<<<dim3(2), BLK, 0, stream>>>(fw1, fw1pk);
    pack_sgn1_kernel<<<blocksForThreads(256 * 69), BLK, 0, stream>>>(w[0], sgnf);

    // layer 1: register-tiled f32 pass + f64 fixup of near-zero outputs
    conv1_pass1_kernel<<<dim3(128, 2, 16), BLK, 0, stream>>>(
        x, sgnf, b[0], sw[0], sb[0], opk16, uflag16);
    conv1_fixup_kernel<<<blocksForThreads(128 * 482 * 16), BLK, 0, stream>>>(
        x, w[0], b[0], sw[0], sb[0], uflag16, opk16);

    // layer 2: K=13 dil=3 pool(3,1): Lin=482 Lconv=446 Lout=149
    {
        const int NLPG = (149 + 3) / 4;
        int nw = 128 * NLPG * 4;
        bconv_bit_kernel<13, 3, 3, 1, 4, 4><<<blocksForWaves(nw), BLK, 0, stream>>>(
            a1, wpk2, b[1], sw[1], sb[1], a2, 256, 482, 446, 149, NLPG, nw);
    }
    // layer 3: K=7 dil=2 pool(3,1): Lin=149 Lconv=137 Lout=46
    {
        const int NLPG = (46 + 3) / 4;
        int nw = 128 * NLPG * 4;
        bconv_bit_kernel<7, 2, 3, 1, 4, 4><<<blocksForWaves(nw), BLK, 0, stream>>>(
            a2, wpk3, b[2], sw[2], sb[2], a3, 256, 149, 137, 46, NLPG, nw);
    }
    // fused tail: layers 4,5,6 + fc1 + fc2
    tail_kernel<<<dim3(128), BLK, 0, stream>>>(
        a3, wpk4, wpk5, wpk6,
        b[3], sw[3], sb[3], b[4], sw[4], sb[4], b[5], sw[5], sb[5],
        fw1pk, fsw1, fsb1, fpk2, fsw2, fsb2, out);
}

// Round 7
// 368.856 us; speedup vs baseline: 5.1941x; 1.0556x over previous
//
#include <hip/hip_runtime.h>
#include <cstdint>
#include <cstddef>

typedef unsigned long long u64;
typedef uint32_t u32;
typedef uint16_t u16;
typedef uint8_t u8;

// ---------------------------------------------------------------------------
// Binary AlexNet-1D. bq(w)=0.1*sign(w), bact(x)=sign(x). All binary layers are
// exact integer XNOR-popcount + f64 affine epilogue. Activations bitpacked as
// [N][L][C/64] u64. Conv sum = CIN*K - 2*popc(a^w); maxpool (stride==kernel,
// scale 0.1>0) commutes with the affine map, so pool the integer sums.
// Layer 1 (real f32 input): register-tiled f32 FMA pass. Thread owns 8 ch x
// 5 conv positions (= one pool window; acc[8][5] in VGPRs). Weights +-1.0f
// staged in LDS (uniform-address broadcast reads), x in LDS tile. Near-zero
// outputs (|v| < margin) recomputed in f64 by a fixup kernel -> sign exact.
// Layers 4..6 + fc1 + fc2 fused into one block-per-sample kernel (LDS).
// ---------------------------------------------------------------------------

#define CONV1_MARGIN 1e-4f

// -------------------- merged weight packing --------------------
// packs w[Cout][CIN][K] float -> wpk[K][Cout][CIN/64]; fc layers use K=1.
struct PackJob { const float* src; u64* dst; int Cout, CIN, K, waveBase; };
struct PackJobs { PackJob j[6]; int totalWaves; };

__global__ void pack_all_kernel(PackJobs P)
{
    int gtid = blockIdx.x * blockDim.x + threadIdx.x;
    int wid = gtid >> 6, lane = gtid & 63;
    if (wid >= P.totalWaves) return;
    int jj = 0;
    #pragma unroll
    for (int i = 1; i < 6; ++i) if (wid >= P.j[i].waveBase) jj = i;
    PackJob job = P.j[jj];
    int lw = wid - job.waveBase;
    int W = job.CIN >> 6;
    int wg = lw % W;
    int co = (lw / W) % job.Cout;
    int k  = lw / (W * job.Cout);
    int ci = wg * 64 + lane;
    bool sg = job.src[((size_t)co * job.CIN + ci) * job.K + k] >= 0.0f;
    u64 word = __ballot(sg);
    if (lane == 0) job.dst[lw] = word;
}

// fc1 weights: fw1[512][32] -> u32[512] sign bitmask (bit i = input i)
__global__ void packfc1_kernel(const float* __restrict__ fw1, u32* __restrict__ fw1pk)
{
    int o = blockIdx.x * blockDim.x + threadIdx.x;
    if (o >= 512) return;
    u32 wd = 0;
    #pragma unroll
    for (int i = 0; i < 32; ++i) wd |= (u32)(fw1[o * 32 + i] >= 0.0f) << i;
    fw1pk[o] = wd;
}

// layer-1 weight signs as f32 +-1.0: sgnf[chunk][i][c], chunk=co/8, c=co%8
__global__ void pack_sgn1_kernel(const float* __restrict__ w1, float* __restrict__ sgnf)
{
    int idx = blockIdx.x * blockDim.x + threadIdx.x;
    if (idx >= 256 * 69) return;
    int i = idx % 69, co = idx / 69;
    sgnf[(size_t)(co >> 3) * 69 * 8 + i * 8 + (co & 7)] =
        (w1[(size_t)co * 69 + i] >= 0.0f) ? 1.0f : -1.0f;
}

// -------------------- layer 1 --------------------
// grid (n=128, bl=2, chunk=32), block 256. Thread tid -> pooled output
// lp = 256*bl + tid for 8 channels [8*chunk, 8*chunk+8).
// conv positions l = 5*lp-2+j, j=0..4 (one pool window, thread-local max).
// x tile + 8-channel weight tile in LDS; acc[8][5] in VGPRs.
__global__ __launch_bounds__(256) void conv1_pass1_kernel(
    const float* __restrict__ x, const float* __restrict__ sgnf,
    const float* __restrict__ b, const float* __restrict__ sw,
    const float* __restrict__ sb,
    u8* __restrict__ opk8, u8* __restrict__ uflag8)
{
    __shared__ float xt[3 * 1440];
    __shared__ float wt[69 * 8];
    const int Lin = 2560, Lconv = 2406;
    int n = blockIdx.x, bl = blockIdx.y, chunk = blockIdx.z;
    int tid = threadIdx.x;
    int base = 1280 * bl - 2;

    // stage x tile (source index clamped; clamped values are only ever read
    // by conv positions that the pooling max later excludes)
    const float* xb = x + (size_t)n * 3 * Lin;
    for (int idx = tid; idx < 3 * 1440; idx += 256) {
        int ci = idx / 1440, rel = idx - ci * 1440;
        int src = min(max(base + rel, 0), Lin - 1);
        xt[idx] = xb[ci * Lin + src];
    }
    // stage weight signs (+-1.0f), layout already [i][c] for this chunk
    for (int idx = tid; idx < 69 * 8; idx += 256)
        wt[idx] = sgnf[(size_t)chunk * 69 * 8 + idx];
    __syncthreads();

    float acc[8][5];
    #pragma unroll
    for (int c = 0; c < 8; ++c)
        #pragma unroll
        for (int j = 0; j < 5; ++j) acc[c][j] = 0.0f;

    const float* xrow = xt + 5 * tid;
    #pragma unroll 1
    for (int ci = 0; ci < 3; ++ci) {
        #pragma unroll
        for (int kk = 0; kk < 23; ++kk) {
            float xv[5];
            #pragma unroll
            for (int j = 0; j < 5; ++j)
                xv[j] = xrow[ci * 1440 + 7 * kk + j];
            const float4* wrow = (const float4*)(wt + (ci * 23 + kk) * 8);
            float4 w0 = wrow[0], w1 = wrow[1];
            float wv[8] = {w0.x, w0.y, w0.z, w0.w, w1.x, w1.y, w1.z, w1.w};
            #pragma unroll
            for (int c = 0; c < 8; ++c)
                #pragma unroll
                for (int j = 0; j < 5; ++j)
                    acc[c][j] = fmaf(xv[j], wv[c], acc[c][j]);
        }
    }

    int lp = 256 * bl + tid;
    if (lp < 482) {
        u32 bits = 0, uncs = 0;
        #pragma unroll
        for (int c = 0; c < 8; ++c) {
            int co = chunk * 8 + c;
            float best = -1e30f;
            #pragma unroll
            for (int j = 0; j < 5; ++j) {
                int l = 5 * lp - 2 + j;
                if (l >= 0 && l < Lconv) best = fmaxf(best, acc[c][j]);
            }
            float v = ((sw[co] >= 0.0f) ? 0.1f : -0.1f) * (0.1f * best + b[co]) + sb[co];
            bits |= (v >= 0.0f ? 1u : 0u) << c;
            uncs |= (fabsf(v) < CONV1_MARGIN ? 1u : 0u) << c;
        }
        // byte `chunk` of the [N][L][4]u64 packed layout = channels 8chunk..+7
        size_t bidx = ((size_t)n * 482 + lp) * 32 + chunk;
        opk8[bidx] = (u8)bits;
        uflag8[bidx] = (u8)uncs;
    }
}

// Fixup: thread per packed u8 word; recompute flagged channels in f64.
__global__ void conv1_fixup_kernel(const float* __restrict__ x,
                                   const float* __restrict__ w1,
                                   const float* __restrict__ b,
                                   const float* __restrict__ sw,
                                   const float* __restrict__ sb,
                                   const u8* __restrict__ uflag8,
                                   u8* __restrict__ opk8)
{
    int idx = blockIdx.x * blockDim.x + threadIdx.x;
    if (idx >= 128 * 482 * 32) return;
    u32 f = uflag8[idx];
    if (f == 0) return;
    int chunk = idx & 31;
    int lp = (idx >> 5) % 482;
    int n = idx / (32 * 482);
    u32 word = opk8[idx];
    const float* xb = x + (size_t)n * 3 * 2560;
    while (f) {
        int c = __ffs(f) - 1;
        f &= f - 1;
        int co = chunk * 8 + c;
        const float* wp = w1 + (size_t)co * 69;
        double best = -1e300;
        for (int t = 0; t < 5; ++t) {
            int gl = 5 * lp - 2 + t;
            if (gl < 0 || gl >= 2406) continue;
            double s = 0.0;
            #pragma unroll
            for (int ci = 0; ci < 3; ++ci) {
                const float* xp = xb + ci * 2560 + gl;
                const float* wq = wp + ci * 23;
                #pragma unroll
                for (int kk = 0; kk < 23; ++kk) {
                    double xv = (double)xp[kk * 7];
                    s += (wq[kk] >= 0.0f) ? xv : -xv;
                }
            }
            best = fmax(best, s);
        }
        double v = ((sw[co] >= 0.0f) ? 0.1 : -0.1) * (0.1 * best + (double)b[co]) + (double)sb[co];
        u32 bit = (v >= 0.0) ? 1u : 0u;
        word = (word & ~(1u << c)) | (bit << c);
    }
    opk8[idx] = (u8)word;
}

// -------------------- binary conv layers 2,3 (XNOR-popcount) ---------------
// One wave = 64 output channels x LPW pooled positions at one (n,og).
template<int K, int DIL, int PK, int PP, int W, int LPW>
__global__ void bconv_bit_kernel(const u64* __restrict__ apk,  // [N][Lin][W]
                                 const u64* __restrict__ wpk,  // [K][Cout][W]
                                 const float* __restrict__ b,
                                 const float* __restrict__ sw,
                                 const float* __restrict__ sb,
                                 u64* __restrict__ opk,        // [N][Lout][Cout/64]
                                 int Cout, int Lin, int Lconv, int Lout,
                                 int NLPG, int nwaves)
{
    int wid = __builtin_amdgcn_readfirstlane(
        (int)(blockIdx.x * (blockDim.x >> 6)) + (int)(threadIdx.x >> 6));
    int lane = threadIdx.x & 63;
    if (wid >= nwaves) return;
    int WOUT = Cout >> 6;
    int og = wid % WOUT;
    int lpg = (wid / WOUT) % NLPG;
    int n  = wid / (WOUT * NLPG);
    int lp0 = lpg * LPW;
    int co = og * 64 + lane;

    const u64* ab = apk + (size_t)n * Lin * W;
    int cnt[LPW][PK];
    #pragma unroll
    for (int j = 0; j < LPW; ++j)
        #pragma unroll
        for (int t = 0; t < PK; ++t) cnt[j][t] = 0;

    #pragma unroll
    for (int k = 0; k < K; ++k) {
        u64 ww[W];
        #pragma unroll
        for (int w = 0; w < W; ++w)
            ww[w] = wpk[((size_t)k * Cout + co) * W + w];
        #pragma unroll
        for (int j = 0; j < LPW; ++j) {
            int lp = lp0 + j;
            #pragma unroll
            for (int t = 0; t < PK; ++t) {
                int l = lp * PK - PP + t;
                if (lp >= Lout || l < 0 || l >= Lconv) continue;
                const u64* ap = ab + (size_t)(l + k * DIL) * W;
                #pragma unroll
                for (int w = 0; w < W; ++w)
                    cnt[j][t] += __popcll(ap[w] ^ ww[w]);
            }
        }
    }
    const int CINK = W * 64 * K;
    #pragma unroll
    for (int j = 0; j < LPW; ++j) {
        int lp = lp0 + j;
        int best = -2147483647;
        #pragma unroll
        for (int t = 0; t < PK; ++t) {
            int l = lp * PK - PP + t;
            if (l < 0 || l >= Lconv) continue;
            int ksum = CINK - 2 * cnt[j][t];
            best = (ksum > best) ? ksum : best;
        }
        bool bit = false;
        if (lp < Lout) {
            double conv = 0.1 * (double)best + (double)b[co];
            double v = ((sw[co] >= 0.0f) ? 0.1 : -0.1) * conv + (double)sb[co];
            bit = (v >= 0.0);
        }
        u64 word = __ballot(bit);
        if (lp < Lout && lane == 0)
            opk[((size_t)n * Lout + lp) * WOUT + og] = word;
    }
}

// -------------------- fused tail: layers 4,5,6 + fc1 + fc2 -----------------
// One block (256 threads) per sample n; intermediates live in LDS.
__global__ __launch_bounds__(256) void tail_kernel(
    const u64* __restrict__ a3,      // [128][46][4]
    const u64* __restrict__ wpk4,    // [5][256][4]
    const u64* __restrict__ wpk5,    // [5][256][4]
    const u64* __restrict__ wpk6,    // [3][8][4]
    const float* __restrict__ b4, const float* __restrict__ sw4, const float* __restrict__ sb4,
    const float* __restrict__ b5, const float* __restrict__ sw5, const float* __restrict__ sb5,
    const float* __restrict__ b6, const float* __restrict__ sw6, const float* __restrict__ sb6,
    const u32* __restrict__ fw1pk,   // [512]
    const float* __restrict__ fsw1, const float* __restrict__ fsb1,
    const u64* __restrict__ fpk2,    // [1000][8]
    const float* __restrict__ fsw2, const float* __restrict__ fsb2,
    float* __restrict__ out)         // [128][1000]
{
    __shared__ u64 sA[46 * 4];   // layer-4 input
    __shared__ u64 sB[42 * 4];   // layer-4 output
    __shared__ u64 sC[13 * 4];   // layer-5 output
    __shared__ u32 sA6;          // layer-6 output, 32 bits (bit = co*4+lp)
    __shared__ u64 sH[8];        // fc1 output, 512 bits
    int n = blockIdx.x, tid = threadIdx.x, lane = tid & 63, wv = tid >> 6;

    for (int i = tid; i < 46 * 4; i += 256) sA[i] = a3[(size_t)n * 46 * 4 + i];
    __syncthreads();

    // ---- layer 4: K=5, dil=1, no pool, Lconv=Lout=42, thread = channel ----
    {
        u64 ww[5][4];
        #pragma unroll
        for (int k = 0; k < 5; ++k)
            #pragma unroll
            for (int w = 0; w < 4; ++w)
                ww[k][w] = wpk4[((size_t)k * 256 + tid) * 4 + w];
        double bc = b4[tid];
        double swc = (sw4[tid] >= 0.0f) ? 0.1 : -0.1;
        double sbc = sb4[tid];
        for (int lp = 0; lp < 42; ++lp) {
            int cnt = 0;
            #pragma unroll
            for (int k = 0; k < 5; ++k)
                #pragma unroll
                for (int w = 0; w < 4; ++w)
                    cnt += __popcll(sA[(lp + k) * 4 + w] ^ ww[k][w]);
            int ksum = 256 * 5 - 2 * cnt;
            double v = swc * (0.1 * ksum + bc) + sbc;
            u64 word = __ballot(v >= 0.0);
            if (lane == 0) sB[lp * 4 + wv] = word;
        }
    }
    __syncthreads();

    // ---- layer 5: K=5, pool(3,1), Lconv=38, Lout=13, thread = channel ----
    {
        u64 ww[5][4];
        #pragma unroll
        for (int k = 0; k < 5; ++k)
            #pragma unroll
            for (int w = 0; w < 4; ++w)
                ww[k][w] = wpk5[((size_t)k * 256 + tid) * 4 + w];
        double bc = b5[tid];
        double swc = (sw5[tid] >= 0.0f) ? 0.1 : -0.1;
        double sbc = sb5[tid];
        for (int lp = 0; lp < 13; ++lp) {
            int best = -2147483647;
            #pragma unroll
            for (int t = 0; t < 3; ++t) {
                int l = 3 * lp - 1 + t;
                if (l < 0 || l >= 38) continue;
                int cnt = 0;
                #pragma unroll
                for (int k = 0; k < 5; ++k)
                    #pragma unroll
                    for (int w = 0; w < 4; ++w)
                        cnt += __popcll(sB[(l + k) * 4 + w] ^ ww[k][w]);
                int ksum = 256 * 5 - 2 * cnt;
                best = (ksum > best) ? ksum : best;
            }
            double v = swc * (0.1 * best + bc) + sbc;
            u64 word = __ballot(v >= 0.0);
            if (lane == 0) sC[lp * 4 + wv] = word;
        }
    }
    __syncthreads();

    // ---- layer 6: Cout=8, K=3, pool(3,1), Lconv=11, Lout=4 ----
    if (tid < 32) {
        int co = tid >> 2, lp = tid & 3;
        int best = -2147483647;
        for (int t = 0; t < 3; ++t) {
            int l = 3 * lp - 1 + t;
            if (l < 0 || l >= 11) continue;
            int cnt = 0;
            #pragma unroll
            for (int k = 0; k < 3; ++k)
                #pragma unroll
                for (int w = 0; w < 4; ++w)
                    cnt += __popcll(sC[(l + k) * 4 + w] ^ wpk6[((size_t)k * 8 + co) * 4 + w]);
            int ksum = 256 * 3 - 2 * cnt;
            best = (ksum > best) ? ksum : best;
        }
        double v = ((sw6[co] >= 0.0f) ? 0.1 : -0.1) * (0.1 * best + (double)b6[co]) + (double)sb6[co];
        u64 word = __ballot(v >= 0.0);   // bit index = tid = co*4+lp (reshape order)
        if (tid == 0) sA6 = (u32)word;
    }
    __syncthreads();

    // ---- fc1: 512 outputs, 32-bit xnor-popcount ----
    {
        u32 a6w = sA6;
        #pragma unroll
        for (int p = 0; p < 2; ++p) {
            int o = tid + p * 256;
            int k = 32 - 2 * __popc(a6w ^ fw1pk[o]);
            double v = ((fsw1[o] >= 0.0f) ? 0.1 : -0.1) * (0.1 * (double)k) + (double)fsb1[o];
            u64 word = __ballot(v >= 0.0);
            if (lane == 0) sH[p * 4 + wv] = word;
        }
    }
    __syncthreads();

    // ---- fc2: 1000 outputs, 512-bit xnor-popcount, f32 store ----
    {
        u64 h[8];
        #pragma unroll
        for (int w = 0; w < 8; ++w) h[w] = sH[w];
        #pragma unroll
        for (int p = 0; p < 4; ++p) {
            int o = tid + p * 256;
            if (o < 1000) {
                int cnt = 0;
                #pragma unroll
                for (int w = 0; w < 8; ++w)
                    cnt += __popcll(h[w] ^ fpk2[(size_t)o * 8 + w]);
                int k = 512 - 2 * cnt;
                double v = ((fsw2[o] >= 0.0f) ? 0.1 : -0.1) * (0.1 * (double)k) + (double)fsb2[o];
                out[(size_t)n * 1000 + o] = (float)v;
            }
        }
    }
}

extern "C" void kernel_launch(void* const* d_in, const int* in_sizes, int n_in,
                              void* d_out, int out_size, void* d_ws, size_t ws_size,
                              hipStream_t stream) {
    const float* x = (const float*)d_in[0];
    const float *w[6], *b[6], *sw[6], *sb[6];
    for (int i = 0; i < 6; ++i) {
        w[i]  = (const float*)d_in[1 + 4 * i];
        b[i]  = (const float*)d_in[2 + 4 * i];
        sw[i] = (const float*)d_in[3 + 4 * i];
        sb[i] = (const float*)d_in[4 + 4 * i];
    }
    const float* fw1  = (const float*)d_in[25];
    const float* fsw1 = (const float*)d_in[26];
    const float* fsb1 = (const float*)d_in[27];
    const float* fw2  = (const float*)d_in[28];
    const float* fsw2 = (const float*)d_in[29];
    const float* fsb2 = (const float*)d_in[30];
    float* out = (float*)d_out;
    (void)in_sizes; (void)n_in; (void)out_size; (void)ws_size;

    char* wsbase = (char*)d_ws;
    size_t off = 0;
    auto alloc = [&](size_t bytes) -> char* {
        char* p = wsbase + off;
        off = (off + bytes + 255) & ~(size_t)255;
        return p;
    };
    u64* wpk2 = (u64*)alloc((size_t)13 * 256 * 4 * 8);
    u64* wpk3 = (u64*)alloc((size_t)7 * 256 * 4 * 8);
    u64* wpk4 = (u64*)alloc((size_t)5 * 256 * 4 * 8);
    u64* wpk5 = (u64*)alloc((size_t)5 * 256 * 4 * 8);
    u64* wpk6 = (u64*)alloc((size_t)3 * 8 * 4 * 8);
    u64* fpk2 = (u64*)alloc((size_t)1000 * 8 * 8);
    u32* fw1pk = (u32*)alloc((size_t)512 * 4);
    float* sgnf = (float*)alloc((size_t)32 * 69 * 8 * 4);
    u8* uflag8 = (u8*)alloc((size_t)128 * 482 * 32);
    u64* a1   = (u64*)alloc((size_t)128 * 482 * 4 * 8);
    u64* a2   = (u64*)alloc((size_t)128 * 149 * 4 * 8);
    u64* a3   = (u64*)alloc((size_t)128 * 46 * 4 * 8);
    u8* opk8 = (u8*)a1;  // byte `chunk` of u64 word og=chunk/8 = ch 8chunk..+7

    const int BLK = 256;
    auto blocksForWaves = [](int nwaves) { return dim3((unsigned)((nwaves * 64 + 255) / 256)); };
    auto blocksForThreads = [](int n) { return dim3((unsigned)((n + 255) / 256)); };

    // merged weight packing (fc2 job expressed as K=1)
    {
        PackJobs P;
        int base = 0;
        auto setJob = [&](int i, const float* src, u64* dst, int Cout, int CIN, int K) {
            P.j[i] = {src, dst, Cout, CIN, K, base};
            base += K * Cout * (CIN >> 6);
        };
        setJob(0, w[1], wpk2, 256, 256, 13);
        setJob(1, w[2], wpk3, 256, 256, 7);
        setJob(2, w[3], wpk4, 256, 256, 5);
        setJob(3, w[4], wpk5, 256, 256, 5);
        setJob(4, w[5], wpk6, 8, 256, 3);
        setJob(5, fw2, fpk2, 1000, 512, 1);
        P.totalWaves = base;
        pack_all_kernel<<<blocksForWaves(base), BLK, 0, stream>>>(P);
    }
    packfc1_kernel<<<dim3(2), BLK, 0, stream>>>(fw1, fw1pk);
    pack_sgn1_kernel<<<blocksForThreads(256 * 69), BLK, 0, stream>>>(w[0], sgnf);

    // layer 1: register-tiled f32 pass + f64 fixup of near-zero outputs
    conv1_pass1_kernel<<<dim3(128, 2, 32), BLK, 0, stream>>>(
        x, sgnf, b[0], sw[0], sb[0], opk8, uflag8);
    conv1_fixup_kernel<<<blocksForThreads(128 * 482 * 32), BLK, 0, stream>>>(
        x, w[0], b[0], sw[0], sb[0], uflag8, opk8);

    // layer 2: K=13 dil=3 pool(3,1): Lin=482 Lconv=446 Lout=149
    {
        const int NLPG = (149 + 3) / 4;
        int nw = 128 * NLPG * 4;
        bconv_bit_kernel<13, 3, 3, 1, 4, 4><<<blocksForWaves(nw), BLK, 0, stream>>>(
            a1, wpk2, b[1], sw[1], sb[1], a2, 256, 482, 446, 149, NLPG, nw);
    }
    // layer 3: K=7 dil=2 pool(3,1): Lin=149 Lconv=137 Lout=46
    {
        const int NLPG = (46 + 3) / 4;
        int nw = 128 * NLPG * 4;
        bconv_bit_kernel<7, 2, 3, 1, 4, 4><<<blocksForWaves(nw), BLK, 0, stream>>>(
            a2, wpk3, b[2], sw[2], sb[2], a3, 256, 149, 137, 46, NLPG, nw);
    }
    // fused tail: layers 4,5,6 + fc1 + fc2
    tail_kernel<<<dim3(128), BLK, 0, stream>>>(
        a3, wpk4, wpk5, wpk6,
        b[3], sw[3], sb[3], b[4], sw[4], sb[4], b[5], sw[5], sb[5],
        fw1pk, fsw1, fsb1, fpk2, fsw2, fsb2, out);
}

// Round 8
// 354.494 us; speedup vs baseline: 5.4046x; 1.0405x over previous
//
#include <hip/hip_runtime.h>
#include <cstdint>
#include <cstddef>

typedef unsigned long long u64;
typedef uint32_t u32;
typedef uint16_t u16;
typedef uint8_t u8;

// ---------------------------------------------------------------------------
// Binary AlexNet-1D. bq(w)=0.1*sign(w), bact(x)=sign(x). All binary layers are
// exact integer XNOR-popcount + f64 affine epilogue. Activations bitpacked as
// [N][L][C/64] u64. Conv sum = CIN*K - 2*popc(a^w); maxpool (stride==kernel,
// scale 0.1>0) commutes with the affine map, so pool the integer sums.
// Layer 1 (real f32 input): register-tiled f32 FMA pass. Thread owns 16 ch x
// 5 conv positions (= one pool window; acc[16][5] in VGPRs — launch_bounds
// min-waves=2 raises the VGPR budget so the tile stays in VGPRs, no AGPR
// round-trips). Weights +-1.0f in LDS (uniform-address float4 broadcast), x
// in LDS tile. Near-zero outputs (|v| < margin) recomputed in f64 by a fixup
// kernel -> sign decisions stay f64-exact.
// Layers 4..6 + fc1 + fc2 fused into one block-per-sample kernel (LDS).
// ---------------------------------------------------------------------------

#define CONV1_MARGIN 1e-4f

// -------------------- merged weight packing --------------------
// packs w[Cout][CIN][K] float -> wpk[K][Cout][CIN/64]; fc layers use K=1.
struct PackJob { const float* src; u64* dst; int Cout, CIN, K, waveBase; };
struct PackJobs { PackJob j[6]; int totalWaves; };

__global__ void pack_all_kernel(PackJobs P)
{
    int gtid = blockIdx.x * blockDim.x + threadIdx.x;
    int wid = gtid >> 6, lane = gtid & 63;
    if (wid >= P.totalWaves) return;
    int jj = 0;
    #pragma unroll
    for (int i = 1; i < 6; ++i) if (wid >= P.j[i].waveBase) jj = i;
    PackJob job = P.j[jj];
    int lw = wid - job.waveBase;
    int W = job.CIN >> 6;
    int wg = lw % W;
    int co = (lw / W) % job.Cout;
    int k  = lw / (W * job.Cout);
    int ci = wg * 64 + lane;
    bool sg = job.src[((size_t)co * job.CIN + ci) * job.K + k] >= 0.0f;
    u64 word = __ballot(sg);
    if (lane == 0) job.dst[lw] = word;
}

// fc1 weights: fw1[512][32] -> u32[512] sign bitmask (bit i = input i)
__global__ void packfc1_kernel(const float* __restrict__ fw1, u32* __restrict__ fw1pk)
{
    int o = blockIdx.x * blockDim.x + threadIdx.x;
    if (o >= 512) return;
    u32 wd = 0;
    #pragma unroll
    for (int i = 0; i < 32; ++i) wd |= (u32)(fw1[o * 32 + i] >= 0.0f) << i;
    fw1pk[o] = wd;
}

// layer-1 weight signs as f32 +-1.0: sgnf[chunk][i][c], chunk=co/16, c=co%16
__global__ void pack_sgn1_kernel(const float* __restrict__ w1, float* __restrict__ sgnf)
{
    int idx = blockIdx.x * blockDim.x + threadIdx.x;
    if (idx >= 256 * 69) return;
    int i = idx % 69, co = idx / 69;
    sgnf[(size_t)(co >> 4) * 69 * 16 + i * 16 + (co & 15)] =
        (w1[(size_t)co * 69 + i] >= 0.0f) ? 1.0f : -1.0f;
}

// -------------------- layer 1 --------------------
// grid (n=128, bl=2, chunk=16), block 256. Thread tid -> pooled output
// lp = 256*bl + tid for 16 channels [16*chunk, 16*chunk+16).
// conv positions l = 5*lp-2+j, j=0..4 (one pool window, thread-local max).
// x tile + 16-channel weight tile in LDS; acc[16][5] in VGPRs.
__global__ __launch_bounds__(256, 2) void conv1_pass1_kernel(
    const float* __restrict__ x, const float* __restrict__ sgnf,
    const float* __restrict__ b, const float* __restrict__ sw,
    const float* __restrict__ sb,
    u16* __restrict__ opk16, u16* __restrict__ uflag16)
{
    __shared__ float xt[3 * 1440];
    __shared__ float wt[69 * 16];
    const int Lin = 2560, Lconv = 2406;
    int n = blockIdx.x, bl = blockIdx.y, chunk = blockIdx.z;
    int tid = threadIdx.x;
    int base = 1280 * bl - 2;

    // stage x tile (source index clamped; clamped values are only ever read
    // by conv positions that the pooling max later excludes)
    const float* xb = x + (size_t)n * 3 * Lin;
    for (int idx = tid; idx < 3 * 1440; idx += 256) {
        int ci = idx / 1440, rel = idx - ci * 1440;
        int src = min(max(base + rel, 0), Lin - 1);
        xt[idx] = xb[ci * Lin + src];
    }
    // stage weight signs (+-1.0f), layout already [i][c] for this chunk
    for (int idx = tid; idx < 69 * 16; idx += 256)
        wt[idx] = sgnf[(size_t)chunk * 69 * 16 + idx];
    __syncthreads();

    float acc[16][5];
    #pragma unroll
    for (int c = 0; c < 16; ++c)
        #pragma unroll
        for (int j = 0; j < 5; ++j) acc[c][j] = 0.0f;

    const float* xrow = xt + 5 * tid;
    #pragma unroll 1
    for (int ci = 0; ci < 3; ++ci) {
        #pragma unroll
        for (int kk = 0; kk < 23; ++kk) {
            float xv[5];
            #pragma unroll
            for (int j = 0; j < 5; ++j)
                xv[j] = xrow[ci * 1440 + 7 * kk + j];
            const float4* wrow = (const float4*)(wt + (ci * 23 + kk) * 16);
            #pragma unroll
            for (int g = 0; g < 4; ++g) {
                float4 wv = wrow[g];
                #pragma unroll
                for (int j = 0; j < 5; ++j) {
                    acc[g * 4 + 0][j] = fmaf(xv[j], wv.x, acc[g * 4 + 0][j]);
                    acc[g * 4 + 1][j] = fmaf(xv[j], wv.y, acc[g * 4 + 1][j]);
                    acc[g * 4 + 2][j] = fmaf(xv[j], wv.z, acc[g * 4 + 2][j]);
                    acc[g * 4 + 3][j] = fmaf(xv[j], wv.w, acc[g * 4 + 3][j]);
                }
            }
        }
    }

    int lp = 256 * bl + tid;
    if (lp < 482) {
        u32 bits = 0, uncs = 0;
        #pragma unroll
        for (int c = 0; c < 16; ++c) {
            int co = chunk * 16 + c;
            float best = -1e30f;
            #pragma unroll
            for (int j = 0; j < 5; ++j) {
                int l = 5 * lp - 2 + j;
                if (l >= 0 && l < Lconv) best = fmaxf(best, acc[c][j]);
            }
            float v = ((sw[co] >= 0.0f) ? 0.1f : -0.1f) * (0.1f * best + b[co]) + sb[co];
            bits |= (v >= 0.0f ? 1u : 0u) << c;
            uncs |= (fabsf(v) < CONV1_MARGIN ? 1u : 0u) << c;
        }
        size_t widx = ((size_t)n * 482 + lp) * 16 + chunk;
        opk16[widx] = (u16)bits;
        uflag16[widx] = (u16)uncs;
    }
}

// Fixup: thread per packed u16 word; recompute flagged channels in f64.
__global__ void conv1_fixup_kernel(const float* __restrict__ x,
                                   const float* __restrict__ w1,
                                   const float* __restrict__ b,
                                   const float* __restrict__ sw,
                                   const float* __restrict__ sb,
                                   const u16* __restrict__ uflag16,
                                   u16* __restrict__ opk16)
{
    int idx = blockIdx.x * blockDim.x + threadIdx.x;
    if (idx >= 128 * 482 * 16) return;
    u32 f = uflag16[idx];
    if (f == 0) return;
    int chunk = idx & 15;
    int lp = (idx >> 4) % 482;
    int n = idx / (16 * 482);
    u32 word = opk16[idx];
    const float* xb = x + (size_t)n * 3 * 2560;
    while (f) {
        int c = __ffs(f) - 1;
        f &= f - 1;
        int co = chunk * 16 + c;
        const float* wp = w1 + (size_t)co * 69;
        double best = -1e300;
        for (int t = 0; t < 5; ++t) {
            int gl = 5 * lp - 2 + t;
            if (gl < 0 || gl >= 2406) continue;
            double s = 0.0;
            #pragma unroll
            for (int ci = 0; ci < 3; ++ci) {
                const float* xp = xb + ci * 2560 + gl;
                const float* wq = wp + ci * 23;
                #pragma unroll
                for (int kk = 0; kk < 23; ++kk) {
                    double xv = (double)xp[kk * 7];
                    s += (wq[kk] >= 0.0f) ? xv : -xv;
                }
            }
            best = fmax(best, s);
        }
        double v = ((sw[co] >= 0.0f) ? 0.1 : -0.1) * (0.1 * best + (double)b[co]) + (double)sb[co];
        u32 bit = (v >= 0.0) ? 1u : 0u;
        word = (word & ~(1u << c)) | (bit << c);
    }
    opk16[idx] = word;
}

// -------------------- binary conv layers 2,3 (XNOR-popcount) ---------------
// One wave = 64 output channels x LPW pooled positions at one (n,og).
template<int K, int DIL, int PK, int PP, int W, int LPW>
__global__ void bconv_bit_kernel(const u64* __restrict__ apk,  // [N][Lin][W]
                                 const u64* __restrict__ wpk,  // [K][Cout][W]
                                 const float* __restrict__ b,
                                 const float* __restrict__ sw,
                                 const float* __restrict__ sb,
                                 u64* __restrict__ opk,        // [N][Lout][Cout/64]
                                 int Cout, int Lin, int Lconv, int Lout,
                                 int NLPG, int nwaves)
{
    int wid = __builtin_amdgcn_readfirstlane(
        (int)(blockIdx.x * (blockDim.x >> 6)) + (int)(threadIdx.x >> 6));
    int lane = threadIdx.x & 63;
    if (wid >= nwaves) return;
    int WOUT = Cout >> 6;
    int og = wid % WOUT;
    int lpg = (wid / WOUT) % NLPG;
    int n  = wid / (WOUT * NLPG);
    int lp0 = lpg * LPW;
    int co = og * 64 + lane;

    const u64* ab = apk + (size_t)n * Lin * W;
    int cnt[LPW][PK];
    #pragma unroll
    for (int j = 0; j < LPW; ++j)
        #pragma unroll
        for (int t = 0; t < PK; ++t) cnt[j][t] = 0;

    #pragma unroll
    for (int k = 0; k < K; ++k) {
        u64 ww[W];
        #pragma unroll
        for (int w = 0; w < W; ++w)
            ww[w] = wpk[((size_t)k * Cout + co) * W + w];
        #pragma unroll
        for (int j = 0; j < LPW; ++j) {
            int lp = lp0 + j;
            #pragma unroll
            for (int t = 0; t < PK; ++t) {
                int l = lp * PK - PP + t;
                if (lp >= Lout || l < 0 || l >= Lconv) continue;
                const u64* ap = ab + (size_t)(l + k * DIL) * W;
                #pragma unroll
                for (int w = 0; w < W; ++w)
                    cnt[j][t] += __popcll(ap[w] ^ ww[w]);
            }
        }
    }
    const int CINK = W * 64 * K;
    #pragma unroll
    for (int j = 0; j < LPW; ++j) {
        int lp = lp0 + j;
        int best = -2147483647;
        #pragma unroll
        for (int t = 0; t < PK; ++t) {
            int l = lp * PK - PP + t;
            if (l < 0 || l >= Lconv) continue;
            int ksum = CINK - 2 * cnt[j][t];
            best = (ksum > best) ? ksum : best;
        }
        bool bit = false;
        if (lp < Lout) {
            double conv = 0.1 * (double)best + (double)b[co];
            double v = ((sw[co] >= 0.0f) ? 0.1 : -0.1) * conv + (double)sb[co];
            bit = (v >= 0.0);
        }
        u64 word = __ballot(bit);
        if (lp < Lout && lane == 0)
            opk[((size_t)n * Lout + lp) * WOUT + og] = word;
    }
}

// -------------------- fused tail: layers 4,5,6 + fc1 + fc2 -----------------
// One block (256 threads) per sample n; intermediates live in LDS.
__global__ __launch_bounds__(256) void tail_kernel(
    const u64* __restrict__ a3,      // [128][46][4]
    const u64* __restrict__ wpk4,    // [5][256][4]
    const u64* __restrict__ wpk5,    // [5][256][4]
    const u64* __restrict__ wpk6,    // [3][8][4]
    const float* __restrict__ b4, const float* __restrict__ sw4, const float* __restrict__ sb4,
    const float* __restrict__ b5, const float* __restrict__ sw5, const float* __restrict__ sb5,
    const float* __restrict__ b6, const float* __restrict__ sw6, const float* __restrict__ sb6,
    const u32* __restrict__ fw1pk,   // [512]
    const float* __restrict__ fsw1, const float* __restrict__ fsb1,
    const u64* __restrict__ fpk2,    // [1000][8]
    const float* __restrict__ fsw2, const float* __restrict__ fsb2,
    float* __restrict__ out)         // [128][1000]
{
    __shared__ u64 sA[46 * 4];   // layer-4 input
    __shared__ u64 sB[42 * 4];   // layer-4 output
    __shared__ u64 sC[13 * 4];   // layer-5 output
    __shared__ u32 sA6;          // layer-6 output, 32 bits (bit = co*4+lp)
    __shared__ u64 sH[8];        // fc1 output, 512 bits
    int n = blockIdx.x, tid = threadIdx.x, lane = tid & 63, wv = tid >> 6;

    for (int i = tid; i < 46 * 4; i += 256) sA[i] = a3[(size_t)n * 46 * 4 + i];
    __syncthreads();

    // ---- layer 4: K=5, dil=1, no pool, Lconv=Lout=42, thread = channel ----
    {
        u64 ww[5][4];
        #pragma unroll
        for (int k = 0; k < 5; ++k)
            #pragma unroll
            for (int w = 0; w < 4; ++w)
                ww[k][w] = wpk4[((size_t)k * 256 + tid) * 4 + w];
        double bc = b4[tid];
        double swc = (sw4[tid] >= 0.0f) ? 0.1 : -0.1;
        double sbc = sb4[tid];
        for (int lp = 0; lp < 42; ++lp) {
            int cnt = 0;
            #pragma unroll
            for (int k = 0; k < 5; ++k)
                #pragma unroll
                for (int w = 0; w < 4; ++w)
                    cnt += __popcll(sA[(lp + k) * 4 + w] ^ ww[k][w]);
            int ksum = 256 * 5 - 2 * cnt;
            double v = swc * (0.1 * ksum + bc) + sbc;
            u64 word = __ballot(v >= 0.0);
            if (lane == 0) sB[lp * 4 + wv] = word;
        }
    }
    __syncthreads();

    // ---- layer 5: K=5, pool(3,1), Lconv=38, Lout=13, thread = channel ----
    {
        u64 ww[5][4];
        #pragma unroll
        for (int k = 0; k < 5; ++k)
            #pragma unroll
            for (int w = 0; w < 4; ++w)
                ww[k][w] = wpk5[((size_t)k * 256 + tid) * 4 + w];
        double bc = b5[tid];
        double swc = (sw5[tid] >= 0.0f) ? 0.1 : -0.1;
        double sbc = sb5[tid];
        for (int lp = 0; lp < 13; ++lp) {
            int best = -2147483647;
            #pragma unroll
            for (int t = 0; t < 3; ++t) {
                int l = 3 * lp - 1 + t;
                if (l < 0 || l >= 38) continue;
                int cnt = 0;
                #pragma unroll
                for (int k = 0; k < 5; ++k)
                    #pragma unroll
                    for (int w = 0; w < 4; ++w)
                        cnt += __popcll(sB[(l + k) * 4 + w] ^ ww[k][w]);
                int ksum = 256 * 5 - 2 * cnt;
                best = (ksum > best) ? ksum : best;
            }
            double v = swc * (0.1 * best + bc) + sbc;
            u64 word = __ballot(v >= 0.0);
            if (lane == 0) sC[lp * 4 + wv] = word;
        }
    }
    __syncthreads();

    // ---- layer 6: Cout=8, K=3, pool(3,1), Lconv=11, Lout=4 ----
    if (tid < 32) {
        int co = tid >> 2, lp = tid & 3;
        int best = -2147483647;
        for (int t = 0; t < 3; ++t) {
            int l = 3 * lp - 1 + t;
            if (l < 0 || l >= 11) continue;
            int cnt = 0;
            #pragma unroll
            for (int k = 0; k < 3; ++k)
                #pragma unroll
                for (int w = 0; w < 4; ++w)
                    cnt += __popcll(sC[(l + k) * 4 + w] ^ wpk6[((size_t)k * 8 + co) * 4 + w]);
            int ksum = 256 * 3 - 2 * cnt;
            best = (ksum > best) ? ksum : best;
        }
        double v = ((sw6[co] >= 0.0f) ? 0.1 : -0.1) * (0.1 * best + (double)b6[co]) + (double)sb6[co];
        u64 word = __ballot(v >= 0.0);   // bit index = tid = co*4+lp (reshape order)
        if (tid == 0) sA6 = (u32)word;
    }
    __syncthreads();

    // ---- fc1: 512 outputs, 32-bit xnor-popcount ----
    {
        u32 a6w = sA6;
        #pragma unroll
        for (int p = 0; p < 2; ++p) {
            int o = tid + p * 256;
            int k = 32 - 2 * __popc(a6w ^ fw1pk[o]);
            double v = ((fsw1[o] >= 0.0f) ? 0.1 : -0.1) * (0.1 * (double)k) + (double)fsb1[o];
            u64 word = __ballot(v >= 0.0);
            if (lane == 0) sH[p * 4 + wv] = word;
        }
    }
    __syncthreads();

    // ---- fc2: 1000 outputs, 512-bit xnor-popcount, f32 store ----
    {
        u64 h[8];
        #pragma unroll
        for (int w = 0; w < 8; ++w) h[w] = sH[w];
        #pragma unroll
        for (int p = 0; p < 4; ++p) {
            int o = tid + p * 256;
            if (o < 1000) {
                int cnt = 0;
                #pragma unroll
                for (int w = 0; w < 8; ++w)
                    cnt += __popcll(h[w] ^ fpk2[(size_t)o * 8 + w]);
                int k = 512 - 2 * cnt;
                double v = ((fsw2[o] >= 0.0f) ? 0.1 : -0.1) * (0.1 * (double)k) + (double)fsb2[o];
                out[(size_t)n * 1000 + o] = (float)v;
            }
        }
    }
}

extern "C" void kernel_launch(void* const* d_in, const int* in_sizes, int n_in,
                              void* d_out, int out_size, void* d_ws, size_t ws_size,
                              hipStream_t stream) {
    const float* x = (const float*)d_in[0];
    const float *w[6], *b[6], *sw[6], *sb[6];
    for (int i = 0; i < 6; ++i) {
        w[i]  = (const float*)d_in[1 + 4 * i];
        b[i]  = (const float*)d_in[2 + 4 * i];
        sw[i] = (const float*)d_in[3 + 4 * i];
        sb[i] = (const float*)d_in[4 + 4 * i];
    }
    const float* fw1  = (const float*)d_in[25];
    const float* fsw1 = (const float*)d_in[26];
    const float* fsb1 = (const float*)d_in[27];
    const float* fw2  = (const float*)d_in[28];
    const float* fsw2 = (const float*)d_in[29];
    const float* fsb2 = (const float*)d_in[30];
    float* out = (float*)d_out;
    (void)in_sizes; (void)n_in; (void)out_size; (void)ws_size;

    char* wsbase = (char*)d_ws;
    size_t off = 0;
    auto alloc = [&](size_t bytes) -> char* {
        char* p = wsbase + off;
        off = (off + bytes + 255) & ~(size_t)255;
        return p;
    };
    u64* wpk2 = (u64*)alloc((size_t)13 * 256 * 4 * 8);
    u64* wpk3 = (u64*)alloc((size_t)7 * 256 * 4 * 8);
    u64* wpk4 = (u64*)alloc((size_t)5 * 256 * 4 * 8);
    u64* wpk5 = (u64*)alloc((size_t)5 * 256 * 4 * 8);
    u64* wpk6 = (u64*)alloc((size_t)3 * 8 * 4 * 8);
    u64* fpk2 = (u64*)alloc((size_t)1000 * 8 * 8);
    u32* fw1pk = (u32*)alloc((size_t)512 * 4);
    float* sgnf = (float*)alloc((size_t)16 * 69 * 16 * 4);
    u16* uflag16 = (u16*)alloc((size_t)128 * 482 * 16 * 2);
    u64* a1   = (u64*)alloc((size_t)128 * 482 * 4 * 8);
    u64* a2   = (u64*)alloc((size_t)128 * 149 * 4 * 8);
    u64* a3   = (u64*)alloc((size_t)128 * 46 * 4 * 8);
    u16* opk16 = (u16*)a1;  // u16 word (co/16) aliases u64 word (co/64) bits

    const int BLK = 256;
    auto blocksForWaves = [](int nwaves) { return dim3((unsigned)((nwaves * 64 + 255) / 256)); };
    auto blocksForThreads = [](int n) { return dim3((unsigned)((n + 255) / 256)); };

    // merged weight packing (fc2 job expressed as K=1)
    {
        PackJobs P;
        int base = 0;
        auto setJob = [&](int i, const float* src, u64* dst, int Cout, int CIN, int K) {
            P.j[i] = {src, dst, Cout, CIN, K, base};
            base += K * Cout * (CIN >> 6);
        };
        setJob(0, w[1], wpk2, 256, 256, 13);
        setJob(1, w[2], wpk3, 256, 256, 7);
        setJob(2, w[3], wpk4, 256, 256, 5);
        setJob(3, w[4], wpk5, 256, 256, 5);
        setJob(4, w[5], wpk6, 8, 256, 3);
        setJob(5, fw2, fpk2, 1000, 512, 1);
        P.totalWaves = base;
        pack_all_kernel<<<blocksForWaves(base), BLK, 0, stream>>>(P);
    }
    packfc1_kernel<<<dim3(2), BLK, 0, stream>>>(fw1, fw1pk);
    pack_sgn1_kernel<<<blocksForThreads(256 * 69), BLK, 0, stream>>>(w[0], sgnf);

    // layer 1: register-tiled f32 pass + f64 fixup of near-zero outputs
    conv1_pass1_kernel<<<dim3(128, 2, 16), BLK, 0, stream>>>(
        x, sgnf, b[0], sw[0], sb[0], opk16, uflag16);
    conv1_fixup_kernel<<<blocksForThreads(128 * 482 * 16), BLK, 0, stream>>>(
        x, w[0], b[0], sw[0], sb[0], uflag16, opk16);

    // layer 2: K=13 dil=3 pool(3,1): Lin=482 Lconv=446 Lout=149
    {
        const int NLPG = (149 + 3) / 4;
        int nw = 128 * NLPG * 4;
        bconv_bit_kernel<13, 3, 3, 1, 4, 4><<<blocksForWaves(nw), BLK, 0, stream>>>(
            a1, wpk2, b[1], sw[1], sb[1], a2, 256, 482, 446, 149, NLPG, nw);
    }
    // layer 3: K=7 dil=2 pool(3,1): Lin=149 Lconv=137 Lout=46
    {
        const int NLPG = (46 + 3) / 4;
        int nw = 128 * NLPG * 4;
        bconv_bit_kernel<7, 2, 3, 1, 4, 4><<<blocksForWaves(nw), BLK, 0, stream>>>(
            a2, wpk3, b[2], sw[2], sb[2], a3, 256, 149, 137, 46, NLPG, nw);
    }
    // fused tail: layers 4,5,6 + fc1 + fc2
    tail_kernel<<<dim3(128), BLK, 0, stream>>>(
        a3, wpk4, wpk5, wpk6,
        b[3], sw[3], sb[3], b[4], sw[4], sb[4], b[5], sw[5], sb[5],
        fw1pk, fsw1, fsb1, fpk2, fsw2, fsb2, out);
}